// Round 14
// baseline (186.965 us; speedup 1.0000x reference)
//
#include <hip/hip_runtime.h>
#include <hip/hip_bf16.h>

// Problem constants
#define NN 4096
#define FIN 512
#define HID 256
#define NH 4
#define DD 64
#define NCLS 64

typedef short bf16x8 __attribute__((ext_vector_type(8)));
typedef float f32x4 __attribute__((ext_vector_type(4)));
typedef unsigned int u32x4 __attribute__((ext_vector_type(4)));

__device__ __forceinline__ unsigned fbits(float x) {
    return __builtin_bit_cast(unsigned, x);
}
__device__ __forceinline__ unsigned short f2bf_rne(float x) {
    unsigned u = fbits(x);
    unsigned r = (u + 0x7fffu + ((u >> 16) & 1u)) >> 16;
    return (unsigned short)r;
}

// pack 8 f32 -> bf16x8 fragment (truncate) via v_perm (R5/R12-verified).
__device__ __forceinline__ bf16x8 pack8(const float* wv) {
    u32x4 au;
#pragma unroll
    for (int t = 0; t < 4; ++t)
        au[t] = __builtin_amdgcn_perm(fbits(wv[2 * t + 1]), fbits(wv[2 * t]),
                                      0x07060302u);
    return __builtin_bit_cast(bf16x8, au);
}

__device__ __forceinline__ bf16x8 ones_frag() {
    u32x4 au = {0x3f803f80u, 0x3f803f80u, 0x3f803f80u, 0x3f803f80u};
    return __builtin_bit_cast(bf16x8, au);
}

// ---------------------------------------------------------------------------
// Inline MFMA layout probe (R6-verified): logical (row,col) of D element
// (lane, reg) for our fragment-construction convention.
// ---------------------------------------------------------------------------
__device__ __forceinline__ void compute_probe(int m, int quad, int* pi, int* pn) {
    float xv[8], yv[8];
#pragma unroll
    for (int e = 0; e < 8; ++e) {
        xv[e] = (quad == 0 && e == 0) ? (float)(m + 1) : 0.f;
        yv[e] = (quad == 0 && e == 0) ? 1.f : 0.f;
    }
    bf16x8 x1 = pack8(xv), y1 = pack8(yv);
#pragma unroll
    for (int e = 0; e < 8; ++e) {
        xv[e] = (quad == 0 && e == 0) ? 1.f : 0.f;
        yv[e] = (quad == 0 && e == 0) ? (float)(m + 1) : 0.f;
    }
    bf16x8 x2 = pack8(xv), y2 = pack8(yv);
    f32x4 d1 = {}, d2 = {};
    d1 = __builtin_amdgcn_mfma_f32_16x16x32_bf16(x1, y1, d1, 0, 0, 0);
    d2 = __builtin_amdgcn_mfma_f32_16x16x32_bf16(x2, y2, d2, 0, 0, 0);
#pragma unroll
    for (int r = 0; r < 4; ++r) {
        pi[r] = min(15, max(0, (int)d1[r] - 1));
        pn[r] = min(15, max(0, (int)d2[r] - 1));
    }
}

// ---------------------------------------------------------------------------
// Adjacency -> bitmask (4 elems/thread, coalesced).
// ---------------------------------------------------------------------------
__global__ __launch_bounds__(256) void adj_bitmask(const int* __restrict__ Adj,
                                                   unsigned* __restrict__ Adjb) {
    const size_t base = (size_t)blockIdx.x * 1024;
    const int tid = threadIdx.x, lane = tid & 63;
#pragma unroll
    for (int c = 0; c < 4; ++c) {
        size_t gid = base + c * 256 + tid;
        int v = Adj[gid];
        unsigned long long bm = __ballot(v > 0);
        if ((lane & 31) == 0)
            Adjb[gid >> 5] = (unsigned)((lane & 32) ? (bm >> 32) : bm);
    }
}

// ---------------------------------------------------------------------------
// Transpose + f32->bf16:  In[R][C] f32 -> OutT[C][R] bf16. (weights only)
// ---------------------------------------------------------------------------
template <int R, int C>
__global__ __launch_bounds__(256) void transpose_cvt(const float* __restrict__ In,
                                                     unsigned short* __restrict__ OutT) {
    __shared__ float t[32][33];
    const int tid = threadIdx.x;
    const int r0 = blockIdx.y * 32, c0 = blockIdx.x * 32;
    const int rl = tid >> 3, cg = tid & 7;
    float4 v = *(const float4*)&In[(size_t)(r0 + rl) * C + c0 + cg * 4];
    t[rl][cg * 4 + 0] = v.x; t[rl][cg * 4 + 1] = v.y;
    t[rl][cg * 4 + 2] = v.z; t[rl][cg * 4 + 3] = v.w;
    __syncthreads();
    const int cl = tid >> 3, rg = tid & 7;
    ushort4 o;
    o.x = f2bf_rne(t[rg * 4 + 0][cl]);
    o.y = f2bf_rne(t[rg * 4 + 1][cl]);
    o.z = f2bf_rne(t[rg * 4 + 2][cl]);
    o.w = f2bf_rne(t[rg * 4 + 3][cl]);
    *(ushort4*)&OutT[(size_t)(c0 + cl) * R + r0 + rg * 4] = o;
}

// ---------------------------------------------------------------------------
// Shared GEMM-head epilogue: accx partials -> HT (bf16 transposed), src
// score, EP[j]={exp(sd), exp(0.2 sd)}.
// ---------------------------------------------------------------------------
__device__ __forceinline__ void head_epilogue(
    float (*accx)[16][65], unsigned short (*hbf)[64],
    int tid, int hh, int i0, int n0,
    const float* a_src, const float* a_dst,
    unsigned short* HT, float* ssr, float* EP)
{
    const int row = tid >> 4, cg = tid & 15;
    float ps = 0.f, pd = 0.f;
#pragma unroll
    for (int c4 = 0; c4 < 4; ++c4) {
        int col = cg * 4 + c4;
        float val = accx[0][row][col] + accx[1][row][col] +
                    accx[2][row][col] + accx[3][row][col];
        ps += val * a_src[n0 + col];
        pd += val * a_dst[n0 + col];
        hbf[row][col] = f2bf_rne(val);
    }
#pragma unroll
    for (int o = 8; o >= 1; o >>= 1) {
        ps += __shfl_xor(ps, o, 64);
        pd += __shfl_xor(pd, o, 64);
    }
    if (cg == 0) {
        int node = i0 + row;
        ssr[hh * NN + node] = ps;
        EP[(size_t)(hh * NN + node) * 2 + 0] = __expf(pd);
        EP[(size_t)(hh * NN + node) * 2 + 1] = __expf(0.2f * pd);
    }
    __syncthreads();
    const int c = tid >> 2, rq = tid & 3;
    ushort4 o4;
    o4.x = hbf[rq * 4 + 0][c];
    o4.y = hbf[rq * 4 + 1][c];
    o4.z = hbf[rq * 4 + 2][c];
    o4.w = hbf[rq * 4 + 3][c];
    *(ushort4*)&HT[(size_t)(n0 + c) * NN + i0 + rq * 4] = o4;
}

// ---------------------------------------------------------------------------
// Layer-1 fused GEMM head: x[16 rows] x W1-head, 4-wave k-split.
// ---------------------------------------------------------------------------
__global__ __launch_bounds__(256) void gemm_head1(
    const float* __restrict__ x,
    const unsigned short* __restrict__ WT,      // [256][512]
    const float* __restrict__ a_src, const float* __restrict__ a_dst,
    unsigned short* __restrict__ HT,
    float* __restrict__ ssr, float* __restrict__ EP)
{
    __shared__ float accx[4][16][65];
    __shared__ unsigned short hbf[16][64];
    const int tid = threadIdx.x;
    const int lane = tid & 63, sp = tid >> 6;
    const int m = lane & 15, quad = lane >> 4;
    const int hh = blockIdx.x, i0 = blockIdx.y * 16;
    const int n0 = hh * 64;
    int pi[4], pn[4];
    compute_probe(m, quad, pi, pn);
    f32x4 acc[4] = {};
#pragma unroll
    for (int ks = 0; ks < 4; ++ks) {
        const int kb = sp * 128 + ks * 32 + quad * 8;
        const float* Af = x + (size_t)(i0 + m) * FIN + kb;
        float4 a0 = *(const float4*)Af;
        float4 a1 = *(const float4*)(Af + 4);
        float av8[8] = {a0.x, a0.y, a0.z, a0.w, a1.x, a1.y, a1.z, a1.w};
        u32x4 au;
#pragma unroll
        for (int t = 0; t < 4; ++t)
            au[t] = (unsigned)f2bf_rne(av8[2 * t]) |
                    ((unsigned)f2bf_rne(av8[2 * t + 1]) << 16);
        bf16x8 a = __builtin_bit_cast(bf16x8, au);
        bf16x8 b[4];
#pragma unroll
        for (int nt = 0; nt < 4; ++nt)
            b[nt] = *(const bf16x8*)&WT[(size_t)(n0 + nt * 16 + m) * FIN + kb];
#pragma unroll
        for (int nt = 0; nt < 4; ++nt)
            acc[nt] = __builtin_amdgcn_mfma_f32_16x16x32_bf16(a, b[nt], acc[nt], 0, 0, 0);
    }
#pragma unroll
    for (int nt = 0; nt < 4; ++nt)
#pragma unroll
        for (int r = 0; r < 4; ++r)
            accx[sp][pi[r]][nt * 16 + pn[r]] = acc[nt][r];
    __syncthreads();
    head_epilogue(accx, hbf, tid, hh, i0, n0, a_src, a_dst, HT, ssr, EP);
}

// ---------------------------------------------------------------------------
// Layer-2 fused GEMM head with fused 8-way layer-1 combine:
// A(row,k) = elu(Σq num_q / Σq den_q), bf16.  head(k-slice) == sp.
// ---------------------------------------------------------------------------
__global__ __launch_bounds__(256) void gemm_head2(
    const float* __restrict__ numP,             // [8][4096][256]
    const float* __restrict__ denP,             // [8][4][4096]
    const unsigned short* __restrict__ WT,      // [64][256]
    const float* __restrict__ a_src, const float* __restrict__ a_dst,
    unsigned short* __restrict__ HT,
    float* __restrict__ ssr, float* __restrict__ EP)
{
    __shared__ float accx[4][16][65];
    __shared__ unsigned short hbf[16][64];
    const int tid = threadIdx.x;
    const int lane = tid & 63, sp = tid >> 6;
    const int m = lane & 15, quad = lane >> 4;
    const int i0 = blockIdx.x * 16;
    int pi[4], pn[4];
    compute_probe(m, quad, pi, pn);

    float den = 0.f;
#pragma unroll
    for (int q = 0; q < 8; ++q)
        den += denP[((size_t)q * NH + sp) * NN + i0 + m];
    const float rd = 1.f / den;

    f32x4 acc[4] = {};
#pragma unroll
    for (int ks = 0; ks < 2; ++ks) {
        const int kb = sp * 64 + ks * 32 + quad * 8;
        float av8[8] = {};
#pragma unroll
        for (int q = 0; q < 8; ++q) {
            const float* pq = numP + ((size_t)q * NN + (i0 + m)) * HID + kb;
            float4 a0 = *(const float4*)pq;
            float4 a1 = *(const float4*)(pq + 4);
            av8[0] += a0.x; av8[1] += a0.y; av8[2] += a0.z; av8[3] += a0.w;
            av8[4] += a1.x; av8[5] += a1.y; av8[6] += a1.z; av8[7] += a1.w;
        }
        u32x4 au;
#pragma unroll
        for (int t = 0; t < 4; ++t) {
            float v0 = av8[2 * t] * rd;
            float v1 = av8[2 * t + 1] * rd;
            v0 = (v0 > 0.f) ? v0 : (__expf(v0) - 1.f);
            v1 = (v1 > 0.f) ? v1 : (__expf(v1) - 1.f);
            au[t] = (unsigned)f2bf_rne(v0) | ((unsigned)f2bf_rne(v1) << 16);
        }
        bf16x8 a = __builtin_bit_cast(bf16x8, au);
        bf16x8 b[4];
#pragma unroll
        for (int nt = 0; nt < 4; ++nt)
            b[nt] = *(const bf16x8*)&WT[(size_t)(nt * 16 + m) * HID + kb];
#pragma unroll
        for (int nt = 0; nt < 4; ++nt)
            acc[nt] = __builtin_amdgcn_mfma_f32_16x16x32_bf16(a, b[nt], acc[nt], 0, 0, 0);
    }
#pragma unroll
    for (int nt = 0; nt < 4; ++nt)
#pragma unroll
        for (int r = 0; r < 4; ++r)
            accx[sp][pi[r]][nt * 16 + pn[r]] = acc[nt][r];
    __syncthreads();
    head_epilogue(accx, hbf, tid, 0, i0, 0, a_src, a_dst, HT, ssr, EP);
}

// ---------------------------------------------------------------------------
// LDS-pipelined attention core (m97 barrier pattern, R13-verified).
// Block = 4 waves sharing one j-stream staged in LDS; each wave owns IT
// i-tiles.  Per step: ds_write -> barrier -> issue next global loads ->
// compute from LDS.
// ---------------------------------------------------------------------------
template <int IT, int NSTEP>
__device__ __forceinline__ void attn_lds_core(
    const unsigned short* __restrict__ htb,   // head slice [64][NN]
    const unsigned* __restrict__ Adjb,
    const float* __restrict__ ssh,
    const float* __restrict__ eph,
    const int wave_i0, const int jbase,
    const int w, const int lane, const int m, const int quad,
    bf16x8 (*HTb)[256], f32x4 (*EPb)[16],
    f32x4 (&acc)[IT][4], f32x4 (&accd)[IT])
{
    constexpr int NG = NSTEP / 4;
    const bf16x8 ones = ones_frag();
    float E1i[IT], E2i[IT];
    const unsigned* mrow[IT];
    u32x4 mcur[IT], mnext[IT];
#pragma unroll
    for (int t = 0; t < IT; ++t) {
        float ss = ssh[wave_i0 + t * 16 + m];
        E1i[t] = __expf(ss);
        E2i[t] = __expf(0.2f * ss);
        mrow[t] = Adjb + (size_t)(wave_i0 + t * 16 + m) * 128 + (jbase >> 5);
        mcur[t] = *(const u32x4*)mrow[t];
    }
    const size_t hrow = (size_t)(w * 16 + m) * NN;
    bf16x8 htv = *(const bf16x8*)&htb[hrow + jbase + quad * 8];
    const bool epl = (w == 0 && lane < 16);
    f32x4 epv = {};
    if (epl) epv = *(const f32x4*)(eph + 2 * jbase + lane * 4);

    for (int g = 0; g < NG; ++g) {
        if (g + 1 < NG) {
#pragma unroll
            for (int t = 0; t < IT; ++t)
                mnext[t] = *(const u32x4*)(mrow[t] + g * 4 + 4);
        }
#pragma unroll
        for (int si = 0; si < 4; ++si) {
            const int s = g * 4 + si;
            const int buf = si & 1;
            HTb[buf][w * 64 + lane] = htv;
            if (epl) EPb[buf][lane] = epv;
            __syncthreads();
            if (s + 1 < NSTEP) {
                const int kb2 = jbase + (s + 1) * 32;
                htv = *(const bf16x8*)&htb[hrow + kb2 + quad * 8];
                if (epl) epv = *(const f32x4*)(eph + 2 * kb2 + lane * 4);
            }
            f32x4 ep[4];
            bf16x8 bfr[4];
#pragma unroll
            for (int v = 0; v < 4; ++v) ep[v] = EPb[buf][quad * 4 + v];
#pragma unroll
            for (int nt = 0; nt < 4; ++nt) bfr[nt] = HTb[buf][nt * 64 + lane];
#pragma unroll
            for (int t = 0; t < IT; ++t) {
                const unsigned mb = (mcur[t][si] >> (quad * 8)) & 0xffu;
                float wv[8];
#pragma unroll
                for (int u = 0; u < 8; ++u) {
                    float e1 = ep[u >> 1][(2 * u) & 3];
                    float e2 = ep[u >> 1][(2 * u + 1) & 3];
                    float wgt = fmaxf(E1i[t] * e1, E2i[t] * e2);
                    wv[u] = ((mb >> u) & 1u) ? wgt : 0.f;
                }
                bf16x8 av = pack8(wv);
                accd[t] = __builtin_amdgcn_mfma_f32_16x16x32_bf16(av, ones, accd[t], 0, 0, 0);
#pragma unroll
                for (int nt = 0; nt < 4; ++nt)
                    acc[t][nt] = __builtin_amdgcn_mfma_f32_16x16x32_bf16(
                        av, bfr[nt], acc[t][nt], 0, 0, 0);
            }
        }
#pragma unroll
        for (int t = 0; t < IT; ++t) mcur[t] = mnext[t];
    }
    __syncthreads();
}

// ---------------------------------------------------------------------------
// Attention layer 1 (partial): grid (NN/128, NH, 8 j-eighths), 256 thr,
// 3 blocks/CU.  Block covers 128 rows (4 waves x IT=2), j-eighth = 512
// (16 steps).  Writes f32 partial num/den; 8-way combine in gemm_head2.
// ---------------------------------------------------------------------------
__global__ __launch_bounds__(256, 3) void attn_l1(
    const unsigned short* __restrict__ HT,
    const unsigned* __restrict__ Adjb,
    const float* __restrict__ ssr,
    const float* __restrict__ EP,
    float* __restrict__ numP,                // [8][4096][256]
    float* __restrict__ denP)                // [8][4][4096]
{
    __shared__ bf16x8 HTb[2][256];
    __shared__ f32x4 EPb[2][16];
    __shared__ __align__(16) float accx[4][16][68];
    __shared__ float lx[4][16];
    const int tid = threadIdx.x;
    const int lane = tid & 63, w = tid >> 6;
    const int m = lane & 15, quad = lane >> 4;
    const int i0 = blockIdx.x * 128, hh = blockIdx.y, jsp = blockIdx.z;
    int pi[4], pn[4];
    compute_probe(m, quad, pi, pn);

    const unsigned short* htb = HT + (size_t)(hh * 64) * NN;
    const float* eph = EP + (size_t)hh * NN * 2;
    const float* ssh = ssr + hh * NN;

    f32x4 acc[2][4] = {};
    f32x4 accd[2] = {};
    attn_lds_core<2, 16>(htb, Adjb, ssh, eph, i0 + w * 32, jsp * 512,
                         w, lane, m, quad, HTb, EPb, acc, accd);

    const int orow = tid >> 4, ocol = (tid & 15) * 4;
#pragma unroll
    for (int t = 0; t < 2; ++t) {
#pragma unroll
        for (int nt = 0; nt < 4; ++nt)
#pragma unroll
            for (int r = 0; r < 4; ++r)
                accx[w][pi[r]][nt * 16 + pn[r]] = acc[t][nt][r];
#pragma unroll
        for (int r = 0; r < 4; ++r) lx[w][pi[r]] = accd[t][r];
        __syncthreads();
#pragma unroll
        for (int p = 0; p < 4; ++p) {
            int node = i0 + p * 32 + t * 16 + orow;
            f32x4 v = *(const f32x4*)&accx[p][orow][ocol];
            *(f32x4*)&numP[((size_t)jsp * NN + node) * HID + hh * 64 + ocol] = v;
            if (ocol == 0)
                denP[((size_t)jsp * NH + hh) * NN + node] = lx[p][orow];
        }
        __syncthreads();
    }
}

// ---------------------------------------------------------------------------
// Attention layer 2 (partial): grid (NN/128, 16 j-splits), 256 thr.
// ---------------------------------------------------------------------------
__global__ __launch_bounds__(256, 3) void attn_l2(
    const unsigned short* __restrict__ HT,   // [64][4096]
    const unsigned* __restrict__ Adjb,
    const float* __restrict__ ssr,
    const float* __restrict__ EP,
    float* __restrict__ numP,                // [16][4096][64]
    float* __restrict__ denP)                // [16][4096]
{
    __shared__ bf16x8 HTb[2][256];
    __shared__ f32x4 EPb[2][16];
    __shared__ __align__(16) float accx[4][16][68];
    __shared__ float lx[4][16];
    const int tid = threadIdx.x;
    const int lane = tid & 63, w = tid >> 6;
    const int m = lane & 15, quad = lane >> 4;
    const int i0 = blockIdx.x * 128, jsp = blockIdx.y;
    int pi[4], pn[4];
    compute_probe(m, quad, pi, pn);

    f32x4 acc[2][4] = {};
    f32x4 accd[2] = {};
    attn_lds_core<2, 8>(HT, Adjb, ssr, EP, i0 + w * 32, jsp * 256,
                        w, lane, m, quad, HTb, EPb, acc, accd);

    const int orow = tid >> 4, ocol = (tid & 15) * 4;
#pragma unroll
    for (int t = 0; t < 2; ++t) {
#pragma unroll
        for (int nt = 0; nt < 4; ++nt)
#pragma unroll
            for (int r = 0; r < 4; ++r)
                accx[w][pi[r]][nt * 16 + pn[r]] = acc[t][nt][r];
#pragma unroll
        for (int r = 0; r < 4; ++r) lx[w][pi[r]] = accd[t][r];
        __syncthreads();
#pragma unroll
        for (int p = 0; p < 4; ++p) {
            int node = i0 + p * 32 + t * 16 + orow;
            f32x4 v = *(const f32x4*)&accx[p][orow][ocol];
            *(f32x4*)&numP[((size_t)jsp * NN + node) * 64 + ocol] = v;
            if (ocol == 0) denP[(size_t)jsp * NN + node] = lx[p][orow];
        }
        __syncthreads();
    }
}

// ---------------------------------------------------------------------------
// Final combine for layer 2: out = Σ16 num / Σ16 den.
// ---------------------------------------------------------------------------
__global__ __launch_bounds__(256) void combine_out(
    const float* __restrict__ numP, const float* __restrict__ denP,
    float* __restrict__ out)
{
    const int gid = blockIdx.x * 256 + threadIdx.x;
    const int base = gid * 4;
    const int node = base >> 6, col = base & 63;
    float nx = 0.f, ny = 0.f, nz = 0.f, nw = 0.f, den = 0.f;
#pragma unroll
    for (int p = 0; p < 16; ++p) {
        float4 v = *(const float4*)&numP[((size_t)p * NN + node) * 64 + col];
        nx += v.x; ny += v.y; nz += v.z; nw += v.w;
        den += denP[(size_t)p * NN + node];
    }
    float rd = 1.f / den;
    float4 o = make_float4(nx * rd, ny * rd, nz * rd, nw * rd);
    *(float4*)&out[base] = o;
}

// ---------------------------------------------------------------------------
extern "C" void kernel_launch(void* const* d_in, const int* in_sizes, int n_in,
                              void* d_out, int out_size, void* d_ws, size_t ws_size,
                              hipStream_t stream) {
    const float* x      = (const float*)d_in[0];
    const int*   Adj    = (const int*)d_in[1];
    const float* W1     = (const float*)d_in[2];
    const float* a1_src = (const float*)d_in[3];
    const float* a1_dst = (const float*)d_in[4];
    const float* W2     = (const float*)d_in[5];
    const float* a2_src = (const float*)d_in[6];
    const float* a2_dst = (const float*)d_in[7];
    float* out = (float*)d_out;

    float* ws = (float*)d_ws;
    unsigned short* HT1   = (unsigned short*)ws;                   // 524288 f
    float*          numP1 = ws + 524288;                           // 8388608 f
    float*          denP1 = ws + 8912896;                          // 131072 f
    unsigned short* HT2   = (unsigned short*)(ws + 9043968);       // 131072 f
    unsigned short* WT1   = (unsigned short*)(ws + 9175040);       // 65536 f
    unsigned short* WT2   = (unsigned short*)(ws + 9240576);       // 8192 f
    unsigned*       Adjb  = (unsigned*)(ws + 9248768);             // 524288 u32
    float* s1s   = ws + 9773056;   // 16384
    float* EP1   = ws + 9789440;   // 32768
    float* s2s   = ws + 9822208;   // 4096
    float* EP2   = ws + 9826304;   // 8192
    // numP2/denP2 alias the (dead after gemm_head2) numP1 region
    float* numP2 = ws + 524288;     // 4194304 f
    float* denP2 = ws + 4718592;    // 65536 f

    // Prep
    adj_bitmask<<<dim3(16384), 256, 0, stream>>>(Adj, Adjb);
    transpose_cvt<FIN, HID><<<dim3(HID / 32, FIN / 32), 256, 0, stream>>>(W1, WT1);
    transpose_cvt<HID, NCLS><<<dim3(NCLS / 32, HID / 32), 256, 0, stream>>>(W2, WT2);

    // Layer 1
    gemm_head1<<<dim3(NH, NN / 16), 256, 0, stream>>>(
        x, WT1, a1_src, a1_dst, HT1, s1s, EP1);
    attn_l1<<<dim3(NN / 128, NH, 8), 256, 0, stream>>>(
        HT1, Adjb, s1s, EP1, numP1, denP1);

    // Layer 2 (8-way combine fused into the GEMM A-path)
    gemm_head2<<<dim3(NN / 16), 256, 0, stream>>>(
        numP1, denP1, WT2, a2_src, a2_dst, HT2, s2s, EP2);
    attn_l2<<<dim3(NN / 128, 16), 256, 0, stream>>>(
        HT2, Adjb, s2s, EP2, numP2, denP2);
    combine_out<<<dim3(256), 256, 0, stream>>>(numP2, denP2, out);
}

// Round 15
// 175.081 us; speedup vs baseline: 1.0679x; 1.0679x over previous
//
#include <hip/hip_runtime.h>
#include <hip/hip_bf16.h>

// Problem constants
#define NN 4096
#define FIN 512
#define HID 256
#define NH 4
#define DD 64
#define NCLS 64

typedef short bf16x8 __attribute__((ext_vector_type(8)));
typedef float f32x4 __attribute__((ext_vector_type(4)));
typedef unsigned int u32x4 __attribute__((ext_vector_type(4)));

__device__ __forceinline__ unsigned fbits(float x) {
    return __builtin_bit_cast(unsigned, x);
}
__device__ __forceinline__ unsigned short f2bf_rne(float x) {
    unsigned u = fbits(x);
    unsigned r = (u + 0x7fffu + ((u >> 16) & 1u)) >> 16;
    return (unsigned short)r;
}

// pack 8 f32 -> bf16x8 fragment (truncate) via v_perm (R5/R12-verified).
__device__ __forceinline__ bf16x8 pack8(const float* wv) {
    u32x4 au;
#pragma unroll
    for (int t = 0; t < 4; ++t)
        au[t] = __builtin_amdgcn_perm(fbits(wv[2 * t + 1]), fbits(wv[2 * t]),
                                      0x07060302u);
    return __builtin_bit_cast(bf16x8, au);
}

__device__ __forceinline__ bf16x8 ones_frag() {
    u32x4 au = {0x3f803f80u, 0x3f803f80u, 0x3f803f80u, 0x3f803f80u};
    return __builtin_bit_cast(bf16x8, au);
}

// ---------------------------------------------------------------------------
// Inline MFMA layout probe (R6-verified): logical (row,col) of D element
// (lane, reg) for our fragment-construction convention.
// ---------------------------------------------------------------------------
__device__ __forceinline__ void compute_probe(int m, int quad, int* pi, int* pn) {
    float xv[8], yv[8];
#pragma unroll
    for (int e = 0; e < 8; ++e) {
        xv[e] = (quad == 0 && e == 0) ? (float)(m + 1) : 0.f;
        yv[e] = (quad == 0 && e == 0) ? 1.f : 0.f;
    }
    bf16x8 x1 = pack8(xv), y1 = pack8(yv);
#pragma unroll
    for (int e = 0; e < 8; ++e) {
        xv[e] = (quad == 0 && e == 0) ? 1.f : 0.f;
        yv[e] = (quad == 0 && e == 0) ? (float)(m + 1) : 0.f;
    }
    bf16x8 x2 = pack8(xv), y2 = pack8(yv);
    f32x4 d1 = {}, d2 = {};
    d1 = __builtin_amdgcn_mfma_f32_16x16x32_bf16(x1, y1, d1, 0, 0, 0);
    d2 = __builtin_amdgcn_mfma_f32_16x16x32_bf16(x2, y2, d2, 0, 0, 0);
#pragma unroll
    for (int r = 0; r < 4; ++r) {
        pi[r] = min(15, max(0, (int)d1[r] - 1));
        pn[r] = min(15, max(0, (int)d2[r] - 1));
    }
}

// ---------------------------------------------------------------------------
// Adjacency -> bitmask (4 elems/thread, coalesced).
// ---------------------------------------------------------------------------
__global__ __launch_bounds__(256) void adj_bitmask(const int* __restrict__ Adj,
                                                   unsigned* __restrict__ Adjb) {
    const size_t base = (size_t)blockIdx.x * 1024;
    const int tid = threadIdx.x, lane = tid & 63;
#pragma unroll
    for (int c = 0; c < 4; ++c) {
        size_t gid = base + c * 256 + tid;
        int v = Adj[gid];
        unsigned long long bm = __ballot(v > 0);
        if ((lane & 31) == 0)
            Adjb[gid >> 5] = (unsigned)((lane & 32) ? (bm >> 32) : bm);
    }
}

// ---------------------------------------------------------------------------
// Both weight transposes in ONE launch.  z=0: W1 [512][256] -> WT1
// [256][512]; z=1: W2 [256][64] -> WT2 [64][256].  Early exit is
// block-uniform (no divergent barrier).
// ---------------------------------------------------------------------------
__global__ __launch_bounds__(256) void transpose_w(
    const float* __restrict__ W1, unsigned short* __restrict__ WT1,
    const float* __restrict__ W2, unsigned short* __restrict__ WT2) {
    __shared__ float t[32][33];
    const int tid = threadIdx.x;
    const float* In;
    unsigned short* OutT;
    int R, C;
    if (blockIdx.z == 0) {
        R = FIN; C = HID; In = W1; OutT = WT1;
    } else {
        if (blockIdx.x >= NCLS / 32 || blockIdx.y >= HID / 32) return;
        R = HID; C = NCLS; In = W2; OutT = WT2;
    }
    const int r0 = blockIdx.y * 32, c0 = blockIdx.x * 32;
    const int rl = tid >> 3, cg = tid & 7;
    float4 v = *(const float4*)&In[(size_t)(r0 + rl) * C + c0 + cg * 4];
    t[rl][cg * 4 + 0] = v.x; t[rl][cg * 4 + 1] = v.y;
    t[rl][cg * 4 + 2] = v.z; t[rl][cg * 4 + 3] = v.w;
    __syncthreads();
    const int cl = tid >> 3, rg = tid & 7;
    ushort4 o;
    o.x = f2bf_rne(t[rg * 4 + 0][cl]);
    o.y = f2bf_rne(t[rg * 4 + 1][cl]);
    o.z = f2bf_rne(t[rg * 4 + 2][cl]);
    o.w = f2bf_rne(t[rg * 4 + 3][cl]);
    *(ushort4*)&OutT[(size_t)(c0 + cl) * R + r0 + rg * 4] = o;
}

// ---------------------------------------------------------------------------
// Shared GEMM-head epilogue: accx partials -> HT (bf16 transposed), src
// score, EP[j]={exp(sd), exp(0.2 sd)}.
// ---------------------------------------------------------------------------
__device__ __forceinline__ void head_epilogue(
    float (*accx)[16][65], unsigned short (*hbf)[64],
    int tid, int hh, int i0, int n0,
    const float* a_src, const float* a_dst,
    unsigned short* HT, float* ssr, float* EP)
{
    const int row = tid >> 4, cg = tid & 15;
    float ps = 0.f, pd = 0.f;
#pragma unroll
    for (int c4 = 0; c4 < 4; ++c4) {
        int col = cg * 4 + c4;
        float val = accx[0][row][col] + accx[1][row][col] +
                    accx[2][row][col] + accx[3][row][col];
        ps += val * a_src[n0 + col];
        pd += val * a_dst[n0 + col];
        hbf[row][col] = f2bf_rne(val);
    }
#pragma unroll
    for (int o = 8; o >= 1; o >>= 1) {
        ps += __shfl_xor(ps, o, 64);
        pd += __shfl_xor(pd, o, 64);
    }
    if (cg == 0) {
        int node = i0 + row;
        ssr[hh * NN + node] = ps;
        EP[(size_t)(hh * NN + node) * 2 + 0] = __expf(pd);
        EP[(size_t)(hh * NN + node) * 2 + 1] = __expf(0.2f * pd);
    }
    __syncthreads();
    const int c = tid >> 2, rq = tid & 3;
    ushort4 o4;
    o4.x = hbf[rq * 4 + 0][c];
    o4.y = hbf[rq * 4 + 1][c];
    o4.z = hbf[rq * 4 + 2][c];
    o4.w = hbf[rq * 4 + 3][c];
    *(ushort4*)&HT[(size_t)(n0 + c) * NN + i0 + rq * 4] = o4;
}

// ---------------------------------------------------------------------------
// Layer-1 fused GEMM head: x[16 rows] x W1-head, 4-wave k-split.
// ---------------------------------------------------------------------------
__global__ __launch_bounds__(256) void gemm_head1(
    const float* __restrict__ x,
    const unsigned short* __restrict__ WT,      // [256][512]
    const float* __restrict__ a_src, const float* __restrict__ a_dst,
    unsigned short* __restrict__ HT,
    float* __restrict__ ssr, float* __restrict__ EP)
{
    __shared__ float accx[4][16][65];
    __shared__ unsigned short hbf[16][64];
    const int tid = threadIdx.x;
    const int lane = tid & 63, sp = tid >> 6;
    const int m = lane & 15, quad = lane >> 4;
    const int hh = blockIdx.x, i0 = blockIdx.y * 16;
    const int n0 = hh * 64;
    int pi[4], pn[4];
    compute_probe(m, quad, pi, pn);
    f32x4 acc[4] = {};
#pragma unroll
    for (int ks = 0; ks < 4; ++ks) {
        const int kb = sp * 128 + ks * 32 + quad * 8;
        const float* Af = x + (size_t)(i0 + m) * FIN + kb;
        float4 a0 = *(const float4*)Af;
        float4 a1 = *(const float4*)(Af + 4);
        float av8[8] = {a0.x, a0.y, a0.z, a0.w, a1.x, a1.y, a1.z, a1.w};
        u32x4 au;
#pragma unroll
        for (int t = 0; t < 4; ++t)
            au[t] = (unsigned)f2bf_rne(av8[2 * t]) |
                    ((unsigned)f2bf_rne(av8[2 * t + 1]) << 16);
        bf16x8 a = __builtin_bit_cast(bf16x8, au);
        bf16x8 b[4];
#pragma unroll
        for (int nt = 0; nt < 4; ++nt)
            b[nt] = *(const bf16x8*)&WT[(size_t)(n0 + nt * 16 + m) * FIN + kb];
#pragma unroll
        for (int nt = 0; nt < 4; ++nt)
            acc[nt] = __builtin_amdgcn_mfma_f32_16x16x32_bf16(a, b[nt], acc[nt], 0, 0, 0);
    }
#pragma unroll
    for (int nt = 0; nt < 4; ++nt)
#pragma unroll
        for (int r = 0; r < 4; ++r)
            accx[sp][pi[r]][nt * 16 + pn[r]] = acc[nt][r];
    __syncthreads();
    head_epilogue(accx, hbf, tid, hh, i0, n0, a_src, a_dst, HT, ssr, EP);
}

// ---------------------------------------------------------------------------
// Layer-2 fused GEMM head with fused 4-way layer-1 combine:
// A(row,k) = elu(Σq num_q / Σq den_q), bf16.  head(k-slice) == sp.
// ---------------------------------------------------------------------------
__global__ __launch_bounds__(256) void gemm_head2(
    const float* __restrict__ numP,             // [4][4096][256]
    const float* __restrict__ denP,             // [4][4][4096]
    const unsigned short* __restrict__ WT,      // [64][256]
    const float* __restrict__ a_src, const float* __restrict__ a_dst,
    unsigned short* __restrict__ HT,
    float* __restrict__ ssr, float* __restrict__ EP)
{
    __shared__ float accx[4][16][65];
    __shared__ unsigned short hbf[16][64];
    const int tid = threadIdx.x;
    const int lane = tid & 63, sp = tid >> 6;
    const int m = lane & 15, quad = lane >> 4;
    const int i0 = blockIdx.x * 16;
    int pi[4], pn[4];
    compute_probe(m, quad, pi, pn);

    float den = 0.f;
#pragma unroll
    for (int q = 0; q < 4; ++q)
        den += denP[((size_t)q * NH + sp) * NN + i0 + m];
    const float rd = 1.f / den;

    f32x4 acc[4] = {};
#pragma unroll
    for (int ks = 0; ks < 2; ++ks) {
        const int kb = sp * 64 + ks * 32 + quad * 8;
        float av8[8] = {};
#pragma unroll
        for (int q = 0; q < 4; ++q) {
            const float* pq = numP + ((size_t)q * NN + (i0 + m)) * HID + kb;
            float4 a0 = *(const float4*)pq;
            float4 a1 = *(const float4*)(pq + 4);
            av8[0] += a0.x; av8[1] += a0.y; av8[2] += a0.z; av8[3] += a0.w;
            av8[4] += a1.x; av8[5] += a1.y; av8[6] += a1.z; av8[7] += a1.w;
        }
        u32x4 au;
#pragma unroll
        for (int t = 0; t < 4; ++t) {
            float v0 = av8[2 * t] * rd;
            float v1 = av8[2 * t + 1] * rd;
            v0 = (v0 > 0.f) ? v0 : (__expf(v0) - 1.f);
            v1 = (v1 > 0.f) ? v1 : (__expf(v1) - 1.f);
            au[t] = (unsigned)f2bf_rne(v0) | ((unsigned)f2bf_rne(v1) << 16);
        }
        bf16x8 a = __builtin_bit_cast(bf16x8, au);
        bf16x8 b[4];
#pragma unroll
        for (int nt = 0; nt < 4; ++nt)
            b[nt] = *(const bf16x8*)&WT[(size_t)(nt * 16 + m) * HID + kb];
#pragma unroll
        for (int nt = 0; nt < 4; ++nt)
            acc[nt] = __builtin_amdgcn_mfma_f32_16x16x32_bf16(a, b[nt], acc[nt], 0, 0, 0);
    }
#pragma unroll
    for (int nt = 0; nt < 4; ++nt)
#pragma unroll
        for (int r = 0; r < 4; ++r)
            accx[sp][pi[r]][nt * 16 + pn[r]] = acc[nt][r];
    __syncthreads();
    head_epilogue(accx, hbf, tid, 0, i0, 0, a_src, a_dst, HT, ssr, EP);
}

// ---------------------------------------------------------------------------
// LDS-pipelined attention core (m97 barrier pattern, R13-verified).
// Block = 4 waves sharing one j-stream staged in LDS; each wave owns IT
// i-tiles.  Per step: ds_write -> barrier -> issue next global loads ->
// compute from LDS.
// ---------------------------------------------------------------------------
template <int IT, int NSTEP>
__device__ __forceinline__ void attn_lds_core(
    const unsigned short* __restrict__ htb,   // head slice [64][NN]
    const unsigned* __restrict__ Adjb,
    const float* __restrict__ ssh,
    const float* __restrict__ eph,
    const int wave_i0, const int jbase,
    const int w, const int lane, const int m, const int quad,
    bf16x8 (*HTb)[256], f32x4 (*EPb)[16],
    f32x4 (&acc)[IT][4], f32x4 (&accd)[IT])
{
    constexpr int NG = NSTEP / 4;
    const bf16x8 ones = ones_frag();
    float E1i[IT], E2i[IT];
    const unsigned* mrow[IT];
    u32x4 mcur[IT], mnext[IT];
#pragma unroll
    for (int t = 0; t < IT; ++t) {
        float ss = ssh[wave_i0 + t * 16 + m];
        E1i[t] = __expf(ss);
        E2i[t] = __expf(0.2f * ss);
        mrow[t] = Adjb + (size_t)(wave_i0 + t * 16 + m) * 128 + (jbase >> 5);
        mcur[t] = *(const u32x4*)mrow[t];
    }
    const size_t hrow = (size_t)(w * 16 + m) * NN;
    bf16x8 htv = *(const bf16x8*)&htb[hrow + jbase + quad * 8];
    const bool epl = (w == 0 && lane < 16);
    f32x4 epv = {};
    if (epl) epv = *(const f32x4*)(eph + 2 * jbase + lane * 4);

    for (int g = 0; g < NG; ++g) {
        if (g + 1 < NG) {
#pragma unroll
            for (int t = 0; t < IT; ++t)
                mnext[t] = *(const u32x4*)(mrow[t] + g * 4 + 4);
        }
#pragma unroll
        for (int si = 0; si < 4; ++si) {
            const int s = g * 4 + si;
            const int buf = si & 1;
            HTb[buf][w * 64 + lane] = htv;
            if (epl) EPb[buf][lane] = epv;
            __syncthreads();
            if (s + 1 < NSTEP) {
                const int kb2 = jbase + (s + 1) * 32;
                htv = *(const bf16x8*)&htb[hrow + kb2 + quad * 8];
                if (epl) epv = *(const f32x4*)(eph + 2 * kb2 + lane * 4);
            }
            f32x4 ep[4];
            bf16x8 bfr[4];
#pragma unroll
            for (int v = 0; v < 4; ++v) ep[v] = EPb[buf][quad * 4 + v];
#pragma unroll
            for (int nt = 0; nt < 4; ++nt) bfr[nt] = HTb[buf][nt * 64 + lane];
#pragma unroll
            for (int t = 0; t < IT; ++t) {
                const unsigned mb = (mcur[t][si] >> (quad * 8)) & 0xffu;
                float wv[8];
#pragma unroll
                for (int u = 0; u < 8; ++u) {
                    float e1 = ep[u >> 1][(2 * u) & 3];
                    float e2 = ep[u >> 1][(2 * u + 1) & 3];
                    float wgt = fmaxf(E1i[t] * e1, E2i[t] * e2);
                    wv[u] = ((mb >> u) & 1u) ? wgt : 0.f;
                }
                bf16x8 av = pack8(wv);
                accd[t] = __builtin_amdgcn_mfma_f32_16x16x32_bf16(av, ones, accd[t], 0, 0, 0);
#pragma unroll
                for (int nt = 0; nt < 4; ++nt)
                    acc[t][nt] = __builtin_amdgcn_mfma_f32_16x16x32_bf16(
                        av, bfr[nt], acc[t][nt], 0, 0, 0);
            }
        }
#pragma unroll
        for (int t = 0; t < IT; ++t) mcur[t] = mnext[t];
    }
    __syncthreads();
}

// ---------------------------------------------------------------------------
// Attention layer 1 (partial): grid (NN/128, NH, 4 j-quarters), 256 thr.
// Block covers 128 rows (4 waves x IT=2), j-quarter = 1024 (32 steps).
// Writes f32 partial num/den; 4-way combine fused into gemm_head2.
// ---------------------------------------------------------------------------
__global__ __launch_bounds__(256, 2) void attn_l1(
    const unsigned short* __restrict__ HT,
    const unsigned* __restrict__ Adjb,
    const float* __restrict__ ssr,
    const float* __restrict__ EP,
    float* __restrict__ numP,                // [4][4096][256]
    float* __restrict__ denP)                // [4][4][4096]
{
    __shared__ bf16x8 HTb[2][256];
    __shared__ f32x4 EPb[2][16];
    __shared__ __align__(16) float accx[4][16][68];
    __shared__ float lx[4][16];
    const int tid = threadIdx.x;
    const int lane = tid & 63, w = tid >> 6;
    const int m = lane & 15, quad = lane >> 4;
    const int i0 = blockIdx.x * 128, hh = blockIdx.y, qtr = blockIdx.z;
    int pi[4], pn[4];
    compute_probe(m, quad, pi, pn);

    const unsigned short* htb = HT + (size_t)(hh * 64) * NN;
    const float* eph = EP + (size_t)hh * NN * 2;
    const float* ssh = ssr + hh * NN;

    f32x4 acc[2][4] = {};
    f32x4 accd[2] = {};
    attn_lds_core<2, 32>(htb, Adjb, ssh, eph, i0 + w * 32, qtr * 1024,
                         w, lane, m, quad, HTb, EPb, acc, accd);

    const int orow = tid >> 4, ocol = (tid & 15) * 4;
#pragma unroll
    for (int t = 0; t < 2; ++t) {
#pragma unroll
        for (int nt = 0; nt < 4; ++nt)
#pragma unroll
            for (int r = 0; r < 4; ++r)
                accx[w][pi[r]][nt * 16 + pn[r]] = acc[t][nt][r];
#pragma unroll
        for (int r = 0; r < 4; ++r) lx[w][pi[r]] = accd[t][r];
        __syncthreads();
#pragma unroll
        for (int p = 0; p < 4; ++p) {
            int node = i0 + p * 32 + t * 16 + orow;
            f32x4 v = *(const f32x4*)&accx[p][orow][ocol];
            *(f32x4*)&numP[((size_t)qtr * NN + node) * HID + hh * 64 + ocol] = v;
            if (ocol == 0)
                denP[((size_t)qtr * NH + hh) * NN + node] = lx[p][orow];
        }
        __syncthreads();
    }
}

// ---------------------------------------------------------------------------
// Attention layer 2 (partial): grid (NN/128, 16 j-splits), 256 thr.
// Block covers 128 rows, j-split = 256 (8 steps).
// ---------------------------------------------------------------------------
__global__ __launch_bounds__(256, 2) void attn_l2(
    const unsigned short* __restrict__ HT,   // [64][4096]
    const unsigned* __restrict__ Adjb,
    const float* __restrict__ ssr,
    const float* __restrict__ EP,
    float* __restrict__ numP,                // [16][4096][64]
    float* __restrict__ denP)                // [16][4096]
{
    __shared__ bf16x8 HTb[2][256];
    __shared__ f32x4 EPb[2][16];
    __shared__ __align__(16) float accx[4][16][68];
    __shared__ float lx[4][16];
    const int tid = threadIdx.x;
    const int lane = tid & 63, w = tid >> 6;
    const int m = lane & 15, quad = lane >> 4;
    const int i0 = blockIdx.x * 128, jsp = blockIdx.y;
    int pi[4], pn[4];
    compute_probe(m, quad, pi, pn);

    f32x4 acc[2][4] = {};
    f32x4 accd[2] = {};
    attn_lds_core<2, 8>(HT, Adjb, ssr, EP, i0 + w * 32, jsp * 256,
                        w, lane, m, quad, HTb, EPb, acc, accd);

    const int orow = tid >> 4, ocol = (tid & 15) * 4;
#pragma unroll
    for (int t = 0; t < 2; ++t) {
#pragma unroll
        for (int nt = 0; nt < 4; ++nt)
#pragma unroll
            for (int r = 0; r < 4; ++r)
                accx[w][pi[r]][nt * 16 + pn[r]] = acc[t][nt][r];
#pragma unroll
        for (int r = 0; r < 4; ++r) lx[w][pi[r]] = accd[t][r];
        __syncthreads();
#pragma unroll
        for (int p = 0; p < 4; ++p) {
            int node = i0 + p * 32 + t * 16 + orow;
            f32x4 v = *(const f32x4*)&accx[p][orow][ocol];
            *(f32x4*)&numP[((size_t)jsp * NN + node) * 64 + ocol] = v;
            if (ocol == 0) denP[(size_t)jsp * NN + node] = lx[p][orow];
        }
        __syncthreads();
    }
}

// ---------------------------------------------------------------------------
// Final combine for layer 2: out = Σ16 num / Σ16 den.
// ---------------------------------------------------------------------------
__global__ __launch_bounds__(256) void combine_out(
    const float* __restrict__ numP, const float* __restrict__ denP,
    float* __restrict__ out)
{
    const int gid = blockIdx.x * 256 + threadIdx.x;
    const int base = gid * 4;
    const int node = base >> 6, col = base & 63;
    float nx = 0.f, ny = 0.f, nz = 0.f, nw = 0.f, den = 0.f;
#pragma unroll
    for (int p = 0; p < 16; ++p) {
        float4 v = *(const float4*)&numP[((size_t)p * NN + node) * 64 + col];
        nx += v.x; ny += v.y; nz += v.z; nw += v.w;
        den += denP[(size_t)p * NN + node];
    }
    float rd = 1.f / den;
    float4 o = make_float4(nx * rd, ny * rd, nz * rd, nw * rd);
    *(float4*)&out[base] = o;
}

// ---------------------------------------------------------------------------
extern "C" void kernel_launch(void* const* d_in, const int* in_sizes, int n_in,
                              void* d_out, int out_size, void* d_ws, size_t ws_size,
                              hipStream_t stream) {
    const float* x      = (const float*)d_in[0];
    const int*   Adj    = (const int*)d_in[1];
    const float* W1     = (const float*)d_in[2];
    const float* a1_src = (const float*)d_in[3];
    const float* a1_dst = (const float*)d_in[4];
    const float* W2     = (const float*)d_in[5];
    const float* a2_src = (const float*)d_in[6];
    const float* a2_dst = (const float*)d_in[7];
    float* out = (float*)d_out;

    float* ws = (float*)d_ws;
    unsigned short* HT1   = (unsigned short*)ws;                   // 524288 f
    float*          numP1 = ws + 524288;                           // 4194304 f
    float*          denP1 = ws + 4718592;                          // 65536 f
    unsigned short* HT2   = (unsigned short*)(ws + 4784128);       // 131072 f
    unsigned short* WT1   = (unsigned short*)(ws + 4915200);       // 65536 f
    unsigned short* WT2   = (unsigned short*)(ws + 4980736);       // 8192 f
    unsigned*       Adjb  = (unsigned*)(ws + 4988928);             // 524288 u32
    float* s1s   = ws + 5513216;   // 16384
    float* EP1   = ws + 5529600;   // 32768
    float* s2s   = ws + 5562368;   // 4096
    float* EP2   = ws + 5566464;   // 8192
    float* numP2 = ws + 5574656;   // 4194304
    float* denP2 = ws + 9768960;   // 65536

    // Prep
    adj_bitmask<<<dim3(16384), 256, 0, stream>>>(Adj, Adjb);
    transpose_w<<<dim3(HID / 32, FIN / 32, 2), 256, 0, stream>>>(W1, WT1, W2, WT2);

    // Layer 1
    gemm_head1<<<dim3(NH, NN / 16), 256, 0, stream>>>(
        x, WT1, a1_src, a1_dst, HT1, s1s, EP1);
    attn_l1<<<dim3(NN / 128, NH, 4), 256, 0, stream>>>(
        HT1, Adjb, s1s, EP1, numP1, denP1);

    // Layer 2 (4-way combine fused into the GEMM A-path)
    gemm_head2<<<dim3(NN / 16), 256, 0, stream>>>(
        numP1, denP1, WT2, a2_src, a2_dst, HT2, s2s, EP2);
    attn_l2<<<dim3(NN / 128, 16), 256, 0, stream>>>(
        HT2, Adjb, s2s, EP2, numP2, denP2);
    combine_out<<<dim3(256), 256, 0, stream>>>(numP2, denP2, out);
}